// Round 4
// baseline (168.925 us; speedup 1.0000x reference)
//
#include <hip/hip_runtime.h>
#include <hip/hip_bf16.h>
#include <math.h>

#define NA 250000
#define NG 64
#define NP 4096

// kernel1 geometry
#define GPB 8                       // GTs per pass1 block
#define GGRP (NG / GPB)             // 8
#define SLICES 64
#define SLICE_SPAN 4096             // 64*4096 = 262144 >= NA
#define P1_BLOCKS (SLICES * GGRP)   // 512
#define RBLK (NP / 256)             // 16
#define K1_BLOCKS (P1_BLOCKS + RBLK + 1)   // 529 (last = writer)

// kernel2 geometry
#define ABLK ((NA + 255) / 256)     // 977

// ws float layout
#define OFF_GTP  0                          // 64 rows x 8: x0,y0,x1,y1,area,score,conf,pad
#define OFF_BEST (OFF_GTP + NG * 8)         // [g][slice] partial maxima (g-major, 64/row)
#define OFF_ROI  (OFF_BEST + NG * SLICES)   // 16 x 2 ROI block partials
#define OFF_ACC  (OFF_ROI + RBLK * 2)       // acc[4]: pos,neg,slpos,bce (f32 atomics)
#define OFF_CNT  (OFF_ACC + 8)              // unsigned done-counter for k2

// ---------- shared math helpers ----------

// IoU must be bitwise identical between pass1 (per-GT max) and the matcher
// (force test `iou == best_per_gt`): contraction pinned off; division is a
// deterministic v_rcp_f32 + mul at both call sites (same inlined ops).
static __device__ __forceinline__ float iou_one(
    float gx0, float gy0, float gx1, float gy1, float ga,
    float ax0, float ay0, float ax1, float ay1, float aa)
{
#pragma clang fp contract(off)
    float ltx = fmaxf(gx0, ax0);
    float lty = fmaxf(gy0, ay0);
    float rbx = fminf(gx1, ax1);
    float rby = fminf(gy1, ay1);
    float w = fmaxf(rbx - ltx, 0.0f);
    float h = fmaxf(rby - lty, 0.0f);
    float inter = w * h;
    float uni = ga + aa - inter;
    return inter * __builtin_amdgcn_rcpf(uni);   // uni > 0 always
}

static __device__ __forceinline__ float smooth_l1_f(float d) {
    const float BETA = 1.0f / 9.0f;
    float ad = fabsf(d);
    return (ad < BETA) ? (0.5f * d * d / BETA) : (ad - 0.5f * BETA);
}

// ---------- kernel 1: pass1 partial maxima + ROI losses + gtp writer ----------

__global__ __launch_bounds__(256) void k1(const float4* __restrict__ anchors,
                                          const float4* __restrict__ gt,
                                          const float* __restrict__ gscore,
                                          const int* __restrict__ gconf,
                                          const float* __restrict__ logits,
                                          const float* __restrict__ breg,
                                          const int* __restrict__ rlab,
                                          const float4* __restrict__ rtgt,
                                          const float* __restrict__ rsc,
                                          float* __restrict__ ws) {
    int t = threadIdx.x;
    int b = blockIdx.x;

    if (b == K1_BLOCKS - 1) {
        // ---- writer block: pack gtp, zero acc + k2 counter ----
        if (t < NG) {
            float4 g = gt[t];
            float* r = ws + OFF_GTP + 8 * t;
            r[0] = g.x; r[1] = g.y; r[2] = g.z; r[3] = g.w;
            r[4] = (g.z - g.x) * (g.w - g.y);
            r[5] = gscore[t];
            r[6] = (float)gconf[t];
            r[7] = 0.0f;
        } else if (t < NG + 4) {
            ws[OFF_ACC + (t - NG)] = 0.0f;
        } else if (t == NG + 4) {
            *(unsigned*)(ws + OFF_CNT) = 0u;
        }
        return;
    }

    if (b >= P1_BLOCKS) {
        // ---- ROI block ----
        __shared__ float rbuf[4][2];
        int rb = b - P1_BLOCKS;
        int p = rb * 256 + t;          // 16*256 == NP exactly, no guard needed
        float l0 = logits[2 * p], l1 = logits[2 * p + 1];
        float mx = fmaxf(l0, l1);
        float lse = mx + logf(expf(l0 - mx) + expf(l1 - mx));
        float s = rsc[p];
        float clsl = -((1.0f - s) * (l0 - lse) + s * (l1 - lse));

        int lbl = rlab[p];
        int cl = lbl < 0 ? 0 : lbl;
        float4 bb = *(const float4*)(breg + 8 * p + 4 * cl);
        float4 tg = rtgt[p];
        float sl = smooth_l1_f(bb.x - tg.x) + smooth_l1_f(bb.y - tg.y) +
                   smooth_l1_f(bb.z - tg.z) + smooth_l1_f(bb.w - tg.w);
        float boxl = (lbl > 0) ? sl : 0.0f;

        int lane = t & 63, w = t >> 6;
        for (int off = 32; off > 0; off >>= 1) {
            clsl += __shfl_down(clsl, off);
            boxl += __shfl_down(boxl, off);
        }
        if (lane == 0) { rbuf[w][0] = clsl; rbuf[w][1] = boxl; }
        __syncthreads();
        if (t == 0) {
            float s0 = 0.f, s1 = 0.f;
            for (int i = 0; i < 4; i++) { s0 += rbuf[i][0]; s1 += rbuf[i][1]; }
            ws[OFF_ROI + 2 * rb] = s0;
            ws[OFF_ROI + 2 * rb + 1] = s1;
        }
        return;
    }

    // ---- pass1 block: 8 GTs x 4096 anchors -> wsBest[g][slice] ----
    __shared__ float swm[4][GPB];
    int slice = b >> 3;        // consecutive blocks share a slice -> L2 reuse
    int ggrp = b & 7;
    int g0 = ggrp * GPB;

    float gx0[GPB], gy0[GPB], gx1[GPB], gy1[GPB], ga[GPB];
#pragma unroll
    for (int i = 0; i < GPB; i++) {
        float4 gb = gt[g0 + i];                // uniform -> s_load
        gx0[i] = gb.x; gy0[i] = gb.y; gx1[i] = gb.z; gy1[i] = gb.w;
        ga[i] = (gb.z - gb.x) * (gb.w - gb.y);
    }

    float m[GPB];
#pragma unroll
    for (int i = 0; i < GPB; i++) m[i] = 0.0f;

    int base = slice * SLICE_SPAN + t;
#pragma unroll 4
    for (int k = 0; k < SLICE_SPAN / 256; k++) {
        int a = base + k * 256;
        float4 v = (a < NA) ? anchors[a] : make_float4(0.f, 0.f, 0.f, 0.f);
        float aa = (v.z - v.x) * (v.w - v.y);  // zero box -> iou 0, harmless
#pragma unroll
        for (int i = 0; i < GPB; i++)
            m[i] = fmaxf(m[i], iou_one(gx0[i], gy0[i], gx1[i], gy1[i], ga[i],
                                       v.x, v.y, v.z, v.w, aa));
    }
    int lane = t & 63, w = t >> 6;
#pragma unroll
    for (int i = 0; i < GPB; i++) {
        float mm = m[i];
        for (int off = 32; off > 0; off >>= 1)
            mm = fmaxf(mm, __shfl_down(mm, off));
        if (lane == 0) swm[w][i] = mm;
    }
    __syncthreads();
    if (t < GPB) {
        float mm = fmaxf(fmaxf(swm[0][t], swm[1][t]), fmaxf(swm[2][t], swm[3][t]));
        ws[OFF_BEST + (g0 + t) * SLICES + slice] = mm;   // plain store
    }
}

// ---------- kernel 2: per-block best-reduce + matcher + last-block finalize ----------

__global__ __launch_bounds__(256) void k2(const float4* __restrict__ anchors,
                                          const float* __restrict__ objness,
                                          const float4* __restrict__ pdel,
                                          float* __restrict__ ws,
                                          float* __restrict__ out) {
    __shared__ float sbest[NG];
    __shared__ float red[NG][4];
    __shared__ float rbuf[4][4];
    int t = threadIdx.x;
    int lane = t & 63, w = t >> 6;
    const float* __restrict__ gtp = ws + OFF_GTP;

    // prologue: reduce wsBest[g][0..63] -> sbest[g]  (16 KB, L2-hot, coalesced)
    {
        int g = t >> 2, q = t & 3;
        const float4* rp = (const float4*)(ws + OFF_BEST) + g * 16 + q * 4;
        float4 v0 = rp[0], v1 = rp[1], v2 = rp[2], v3 = rp[3];
        float mm = fmaxf(fmaxf(fmaxf(v0.x, v0.y), fmaxf(v0.z, v0.w)),
                         fmaxf(fmaxf(v1.x, v1.y), fmaxf(v1.z, v1.w)));
        mm = fmaxf(mm, fmaxf(fmaxf(fmaxf(v2.x, v2.y), fmaxf(v2.z, v2.w)),
                             fmaxf(fmaxf(v3.x, v3.y), fmaxf(v3.z, v3.w))));
        red[g][q] = mm;
    }
    __syncthreads();
    if (t < NG)
        sbest[t] = fmaxf(fmaxf(red[t][0], red[t][1]), fmaxf(red[t][2], red[t][3]));
    __syncthreads();

    // matcher + RPN losses
    int a = blockIdx.x * 256 + t;
    float posf = 0.f, negf = 0.f, slpos = 0.f, bces = 0.f;
    if (a < NA) {
        float4 av = anchors[a];
        float aarea = (av.z - av.x) * (av.w - av.y);
        float maxv = -1.0f;
        int arg = 0;
        bool force = false;
#pragma unroll 8
        for (int g = 0; g < NG; g++) {
            const float* G = gtp + 8 * g;         // uniform -> s_load
            float v = iou_one(G[0], G[1], G[2], G[3], G[4],
                              av.x, av.y, av.z, av.w, aarea);
            if (v > maxv) { maxv = v; arg = g; }  // first-max == jnp.argmax
            force = force || (v == sbest[g]);     // broadcast ds_read
        }
        int matched = (maxv < 0.3f) ? -1 : ((maxv < 0.7f) ? -2 : arg);
        if (force) matched = arg;
        int cl = matched < 0 ? 0 : matched;

        const float* Gc = gtp + 8 * cl;           // per-lane gather, 2KB L1-hot
        float4 Ac = *(const float4*)Gc;
        float score = Gc[4 + 1], conf = Gc[4 + 2];
        float label = (matched >= 0) ? 1.0f : 0.0f;
        label = fminf(label, score);
        if (matched == -1) label = 0.0f;
        if (matched == -2) label = -1.0f;
        if (conf == 0.0f && matched >= 0) label = -1.0f;

        bool pos = (label >= 1.0f);
        bool neg = (label == 0.0f);
        bool sel = pos || neg;

        float aw = av.z - av.x, ah = av.w - av.y;
        float acx = av.x + 0.5f * aw, acy = av.y + 0.5f * ah;
        float gw = Ac.z - Ac.x, gh = Ac.w - Ac.y;
        float gcx = Ac.x + 0.5f * gw, gcy = Ac.y + 0.5f * gh;
        float t0 = (gcx - acx) / aw;
        float t1 = (gcy - acy) / ah;
        float t2 = logf(gw / aw);
        float t3 = logf(gh / ah);

        float4 pd = pdel[a];
        float sl = smooth_l1_f(pd.x - t0) + smooth_l1_f(pd.y - t1) +
                   smooth_l1_f(pd.z - t2) + smooth_l1_f(pd.w - t3);

        float x = objness[a];
        float y = sel ? fminf(fmaxf(label, 0.0f), 1.0f) : 0.0f;
        float bce = fmaxf(x, 0.0f) - x * y + log1pf(expf(-fabsf(x)));

        posf = pos ? 1.0f : 0.0f;
        negf = neg ? 1.0f : 0.0f;
        slpos = pos ? sl : 0.0f;
        bces = sel ? bce : 0.0f;
    }

    for (int off = 32; off > 0; off >>= 1) {
        posf  += __shfl_down(posf, off);
        negf  += __shfl_down(negf, off);
        slpos += __shfl_down(slpos, off);
        bces  += __shfl_down(bces, off);
    }
    if (lane == 0) { rbuf[w][0] = posf; rbuf[w][1] = negf; rbuf[w][2] = slpos; rbuf[w][3] = bces; }
    __syncthreads();
    if (t == 0) {
        float s0 = 0.f, s1 = 0.f, s2 = 0.f, s3 = 0.f;
        for (int i = 0; i < 4; i++) { s0 += rbuf[i][0]; s1 += rbuf[i][1]; s2 += rbuf[i][2]; s3 += rbuf[i][3]; }
        float* acc = ws + OFF_ACC;
        // native f32 global atomics (counts stay integer-exact < 2^24)
        atomicAdd(&acc[0], s0);
        atomicAdd(&acc[1], s1);
        atomicAdd(&acc[2], s2);
        atomicAdd(&acc[3], s3);
        __threadfence();                                    // release acc-adds
        unsigned old = atomicAdd((unsigned*)(ws + OFF_CNT), 1u);
        if (old == ABLK - 1) {
            __threadfence();                                // acquire
            double c0 = 0.0, c1 = 0.0;
            for (int i = 0; i < RBLK; i++) {                // written by k1: visible
                c0 += (double)ws[OFF_ROI + 2 * i];
                c1 += (double)ws[OFF_ROI + 2 * i + 1];
            }
            double p  = (double)atomicAdd(&acc[0], 0.0f);   // coherent atomic reads
            double n  = (double)atomicAdd(&acc[1], 0.0f);
            double sl = (double)atomicAdd(&acc[2], 0.0f);
            double bc = (double)atomicAdd(&acc[3], 0.0f);
            double ns = p + n;
            out[0] = (float)(bc / ns);           // objectness_loss
            out[1] = (float)(sl / ns);           // rpn_box_loss
            out[2] = (float)(c0 / (double)NP);   // classification_loss
            out[3] = (float)(c1 / (double)NP);   // roi_box_loss
        }
    }
}

extern "C" void kernel_launch(void* const* d_in, const int* in_sizes, int n_in,
                              void* d_out, int out_size, void* d_ws, size_t ws_size,
                              hipStream_t stream) {
    const float4* anchors = (const float4*)d_in[0];
    const float4* gt      = (const float4*)d_in[1];
    const float*  gscore  = (const float*)d_in[2];
    const int*    gconf   = (const int*)d_in[3];
    const float*  objness = (const float*)d_in[4];
    const float4* pdel    = (const float4*)d_in[5];
    const float*  clog    = (const float*)d_in[6];
    const float*  breg    = (const float*)d_in[7];
    const int*    rlab    = (const int*)d_in[8];
    const float4* rtgt    = (const float4*)d_in[9];
    const float*  rsc     = (const float*)d_in[10];

    float* ws = (float*)d_ws;
    float* out = (float*)d_out;

    k1<<<K1_BLOCKS, 256, 0, stream>>>(anchors, gt, gscore, gconf, clog, breg,
                                      rlab, rtgt, rsc, ws);
    k2<<<ABLK, 256, 0, stream>>>(anchors, objness, pdel, ws, out);
}

// Round 5
// 111.789 us; speedup vs baseline: 1.5111x; 1.5111x over previous
//
#include <hip/hip_runtime.h>
#include <hip/hip_bf16.h>
#include <math.h>

#define NA 250000
#define NG 64
#define NP 4096

// kernel A geometry (pass1 + ROI + writer)
#define GPB 8                       // GTs per pass1 block
#define SLICES 64
#define SLICE_SPAN 4096             // 64*4096 >= NA
#define P1_BLOCKS (SLICES * (NG / GPB))     // 512
#define RBLK (NP / 256)             // 16
#define KA_BLOCKS (P1_BLOCKS + RBLK + 1)    // 529 (last = writer)

// kernel B geometry (matcher, 2 anchors/thread)
#define APT2 2
#define BBLK ((NA + 256 * APT2 - 1) / (256 * APT2))   // 489

// ws float layout
#define OFF_GTP  0                          // 64 x 8: x0,y0,x1,y1,area,score,conf,pad
#define OFF_BEST (OFF_GTP + NG * 8)         // [g][slice] partial maxima
#define OFF_ROI  (OFF_BEST + NG * SLICES)   // 16 x 2 ROI block partials
#define OFF_SUM  (OFF_ROI + RBLK * 2)       // BBLK x 4 matcher block partials

// ---------- shared math helpers ----------

// IoU must be bitwise identical between pass1 (per-GT max) and the matcher
// (force test `iou == best_per_gt`): contraction pinned off; division is a
// deterministic v_rcp_f32 + mul at both call sites (same inlined ops).
static __device__ __forceinline__ float iou_one(
    float gx0, float gy0, float gx1, float gy1, float ga,
    float ax0, float ay0, float ax1, float ay1, float aa)
{
#pragma clang fp contract(off)
    float ltx = fmaxf(gx0, ax0);
    float lty = fmaxf(gy0, ay0);
    float rbx = fminf(gx1, ax1);
    float rby = fminf(gy1, ay1);
    float w = fmaxf(rbx - ltx, 0.0f);
    float h = fmaxf(rby - lty, 0.0f);
    float inter = w * h;
    float uni = ga + aa - inter;
    return inter * __builtin_amdgcn_rcpf(uni);   // uni > 0 always
}

static __device__ __forceinline__ float smooth_l1_f(float d) {
    const float BETA = 1.0f / 9.0f;
    float ad = fabsf(d);
    return (ad < BETA) ? (0.5f * d * d / BETA) : (ad - 0.5f * BETA);
}

// per-anchor matcher epilogue: label logic + box encode + losses
static __device__ __forceinline__ void anchor_tail(
    const float* __restrict__ gtp, const float* __restrict__ objness,
    const float4* __restrict__ pdel, float4 av, float maxv, int arg,
    bool force, bool valid, int a,
    float& posf, float& negf, float& slpos, float& bces)
{
    if (!valid) return;
    int matched = (maxv < 0.3f) ? -1 : ((maxv < 0.7f) ? -2 : arg);
    if (force) matched = arg;
    int cl = matched < 0 ? 0 : matched;

    const float* Gc = gtp + 8 * cl;          // per-lane gather, 2KB L1-hot
    float4 Ac = *(const float4*)Gc;
    float score = Gc[5], conf = Gc[6];
    float label = (matched >= 0) ? 1.0f : 0.0f;
    label = fminf(label, score);
    if (matched == -1) label = 0.0f;
    if (matched == -2) label = -1.0f;
    if (conf == 0.0f && matched >= 0) label = -1.0f;

    bool pos = (label >= 1.0f);
    bool neg = (label == 0.0f);
    bool sel = pos || neg;

    float aw = av.z - av.x, ah = av.w - av.y;
    float acx = av.x + 0.5f * aw, acy = av.y + 0.5f * ah;
    float gw = Ac.z - Ac.x, gh = Ac.w - Ac.y;
    float gcx = Ac.x + 0.5f * gw, gcy = Ac.y + 0.5f * gh;
    float t0 = (gcx - acx) / aw;
    float t1 = (gcy - acy) / ah;
    float t2 = logf(gw / aw);
    float t3 = logf(gh / ah);

    float4 pd = pdel[a];
    float sl = smooth_l1_f(pd.x - t0) + smooth_l1_f(pd.y - t1) +
               smooth_l1_f(pd.z - t2) + smooth_l1_f(pd.w - t3);

    float x = objness[a];
    float y = sel ? fminf(fmaxf(label, 0.0f), 1.0f) : 0.0f;
    float bce = fmaxf(x, 0.0f) - x * y + log1pf(expf(-fabsf(x)));

    if (pos) { posf += 1.0f; slpos += sl; }
    if (neg) negf += 1.0f;
    if (sel) bces += bce;
}

// ---------- kernel A: pass1 partial maxima + ROI losses + gtp writer ----------

__global__ __launch_bounds__(256) void kA(const float4* __restrict__ anchors,
                                          const float4* __restrict__ gt,
                                          const float* __restrict__ gscore,
                                          const int* __restrict__ gconf,
                                          const float* __restrict__ logits,
                                          const float* __restrict__ breg,
                                          const int* __restrict__ rlab,
                                          const float4* __restrict__ rtgt,
                                          const float* __restrict__ rsc,
                                          float* __restrict__ ws) {
    int t = threadIdx.x;
    int b = blockIdx.x;

    if (b == KA_BLOCKS - 1) {
        if (t < NG) {                       // pack uniform GT table
            float4 g = gt[t];
            float* r = ws + OFF_GTP + 8 * t;
            r[0] = g.x; r[1] = g.y; r[2] = g.z; r[3] = g.w;
            r[4] = (g.z - g.x) * (g.w - g.y);
            r[5] = gscore[t];
            r[6] = (float)gconf[t];
            r[7] = 0.0f;
        }
        return;
    }

    if (b >= P1_BLOCKS) {
        // ---- ROI block ----
        __shared__ float rbuf[4][2];
        int rb = b - P1_BLOCKS;
        int p = rb * 256 + t;               // 16*256 == NP
        float l0 = logits[2 * p], l1 = logits[2 * p + 1];
        float mx = fmaxf(l0, l1);
        float lse = mx + logf(expf(l0 - mx) + expf(l1 - mx));
        float s = rsc[p];
        float clsl = -((1.0f - s) * (l0 - lse) + s * (l1 - lse));

        int lbl = rlab[p];
        int cl = lbl < 0 ? 0 : lbl;
        float4 bb = *(const float4*)(breg + 8 * p + 4 * cl);
        float4 tg = rtgt[p];
        float sl = smooth_l1_f(bb.x - tg.x) + smooth_l1_f(bb.y - tg.y) +
                   smooth_l1_f(bb.z - tg.z) + smooth_l1_f(bb.w - tg.w);
        float boxl = (lbl > 0) ? sl : 0.0f;

        int lane = t & 63, w = t >> 6;
        for (int off = 32; off > 0; off >>= 1) {
            clsl += __shfl_down(clsl, off);
            boxl += __shfl_down(boxl, off);
        }
        if (lane == 0) { rbuf[w][0] = clsl; rbuf[w][1] = boxl; }
        __syncthreads();
        if (t == 0) {
            float s0 = 0.f, s1 = 0.f;
            for (int i = 0; i < 4; i++) { s0 += rbuf[i][0]; s1 += rbuf[i][1]; }
            ws[OFF_ROI + 2 * rb] = s0;
            ws[OFF_ROI + 2 * rb + 1] = s1;
        }
        return;
    }

    // ---- pass1 block: 8 GTs x 4096 anchors -> wsBest[g][slice] ----
    __shared__ float swm[4][GPB];
    int slice = b >> 3;            // consecutive blocks share a slice -> L2 reuse
    int ggrp = b & 7;
    int g0 = ggrp * GPB;

    float gx0[GPB], gy0[GPB], gx1[GPB], gy1[GPB], ga[GPB];
#pragma unroll
    for (int i = 0; i < GPB; i++) {
        float4 gb = gt[g0 + i];            // uniform -> s_load
        gx0[i] = gb.x; gy0[i] = gb.y; gx1[i] = gb.z; gy1[i] = gb.w;
        ga[i] = (gb.z - gb.x) * (gb.w - gb.y);
    }

    float m[GPB];
#pragma unroll
    for (int i = 0; i < GPB; i++) m[i] = 0.0f;

    int base = slice * SLICE_SPAN + t;
#pragma unroll 4
    for (int k = 0; k < SLICE_SPAN / 256; k++) {
        int a = base + k * 256;
        float4 v = (a < NA) ? anchors[a] : make_float4(0.f, 0.f, 0.f, 0.f);
        float aa = (v.z - v.x) * (v.w - v.y);  // zero box -> iou 0, harmless
#pragma unroll
        for (int i = 0; i < GPB; i++)
            m[i] = fmaxf(m[i], iou_one(gx0[i], gy0[i], gx1[i], gy1[i], ga[i],
                                       v.x, v.y, v.z, v.w, aa));
    }
    int lane = t & 63, w = t >> 6;
#pragma unroll
    for (int i = 0; i < GPB; i++) {
        float mm = m[i];
        for (int off = 32; off > 0; off >>= 1)
            mm = fmaxf(mm, __shfl_down(mm, off));
        if (lane == 0) swm[w][i] = mm;
    }
    __syncthreads();
    if (t < GPB) {
        float mm = fmaxf(fmaxf(swm[0][t], swm[1][t]), fmaxf(swm[2][t], swm[3][t]));
        ws[OFF_BEST + (g0 + t) * SLICES + slice] = mm;   // plain store
    }
}

// ---------- kernel B: per-block best-reduce + matcher (2 anchors/thread) ----------

__global__ __launch_bounds__(256) void kB(const float4* __restrict__ anchors,
                                          const float* __restrict__ objness,
                                          const float4* __restrict__ pdel,
                                          const float* __restrict__ gtp,
                                          const float4* __restrict__ bestp,
                                          float* __restrict__ sums) {
    __shared__ float sbest[NG];
    __shared__ float red[NG][4];
    __shared__ float rbuf[4][4];
    int t = threadIdx.x;
    int lane = t & 63, w = t >> 6;

    // prologue: reduce bestp[g][0..63] -> sbest[g]  (16 KB, L2-hot, coalesced)
    {
        int g = t >> 2, q = t & 3;
        const float4* rp = bestp + g * 16 + q * 4;
        float4 v0 = rp[0], v1 = rp[1], v2 = rp[2], v3 = rp[3];
        float mm = fmaxf(fmaxf(fmaxf(v0.x, v0.y), fmaxf(v0.z, v0.w)),
                         fmaxf(fmaxf(v1.x, v1.y), fmaxf(v1.z, v1.w)));
        mm = fmaxf(mm, fmaxf(fmaxf(fmaxf(v2.x, v2.y), fmaxf(v2.z, v2.w)),
                             fmaxf(fmaxf(v3.x, v3.y), fmaxf(v3.z, v3.w))));
        red[g][q] = mm;
    }
    __syncthreads();
    if (t < NG)
        sbest[t] = fmaxf(fmaxf(red[t][0], red[t][1]), fmaxf(red[t][2], red[t][3]));
    __syncthreads();

    // two anchors per thread: independent chains, GT fetch amortized
    int a0 = blockIdx.x * (256 * APT2) + t;
    int a1 = a0 + 256;
    bool v0ok = a0 < NA, v1ok = a1 < NA;
    float4 av0 = v0ok ? anchors[a0] : make_float4(0.f, 0.f, 0.f, 0.f);
    float4 av1 = v1ok ? anchors[a1] : make_float4(0.f, 0.f, 0.f, 0.f);
    float aa0 = (av0.z - av0.x) * (av0.w - av0.y);
    float aa1 = (av1.z - av1.x) * (av1.w - av1.y);

    float max0 = -1.0f, max1 = -1.0f;
    int arg0 = 0, arg1 = 0;
    bool f0 = false, f1 = false;
#pragma unroll 8
    for (int g = 0; g < NG; g++) {
        const float* G = gtp + 8 * g;        // uniform -> s_load
        float gx0 = G[0], gy0 = G[1], gx1 = G[2], gy1 = G[3], ga = G[4];
        float sb = sbest[g];                 // broadcast ds_read
        float u0 = iou_one(gx0, gy0, gx1, gy1, ga, av0.x, av0.y, av0.z, av0.w, aa0);
        float u1 = iou_one(gx0, gy0, gx1, gy1, ga, av1.x, av1.y, av1.z, av1.w, aa1);
        if (u0 > max0) { max0 = u0; arg0 = g; }   // first-max == jnp.argmax
        if (u1 > max1) { max1 = u1; arg1 = g; }
        f0 = f0 || (u0 == sb);
        f1 = f1 || (u1 == sb);
    }

    float posf = 0.f, negf = 0.f, slpos = 0.f, bces = 0.f;
    anchor_tail(gtp, objness, pdel, av0, max0, arg0, f0, v0ok, a0,
                posf, negf, slpos, bces);
    anchor_tail(gtp, objness, pdel, av1, max1, arg1, f1, v1ok, a1,
                posf, negf, slpos, bces);

    for (int off = 32; off > 0; off >>= 1) {
        posf  += __shfl_down(posf, off);
        negf  += __shfl_down(negf, off);
        slpos += __shfl_down(slpos, off);
        bces  += __shfl_down(bces, off);
    }
    if (lane == 0) { rbuf[w][0] = posf; rbuf[w][1] = negf; rbuf[w][2] = slpos; rbuf[w][3] = bces; }
    __syncthreads();
    if (t == 0) {
        float s0 = 0.f, s1 = 0.f, s2 = 0.f, s3 = 0.f;
        for (int i = 0; i < 4; i++) { s0 += rbuf[i][0]; s1 += rbuf[i][1]; s2 += rbuf[i][2]; s3 += rbuf[i][3]; }
        float* r = sums + 4 * blockIdx.x;
        r[0] = s0; r[1] = s1; r[2] = s2; r[3] = s3;   // plain stores, no atomics
    }
}

// ---------- kernel C: final reduce (1 block, doubles) ----------

__global__ __launch_bounds__(256) void kC(const float* __restrict__ ws,
                                          float* __restrict__ out) {
    __shared__ double sred[4][6];
    int t = threadIdx.x;
    int lane = t & 63, w = t >> 6;
    double a0 = 0, a1 = 0, a2 = 0, a3 = 0, c0 = 0, c1 = 0;
    for (int r = t; r < BBLK; r += 256) {
        const float4 v = *(const float4*)(ws + OFF_SUM + 4 * r);
        a0 += v.x; a1 += v.y; a2 += v.z; a3 += v.w;
    }
    if (t < RBLK) {
        c0 = ws[OFF_ROI + 2 * t];
        c1 = ws[OFF_ROI + 2 * t + 1];
    }
    for (int off = 32; off > 0; off >>= 1) {
        a0 += __shfl_down(a0, off);
        a1 += __shfl_down(a1, off);
        a2 += __shfl_down(a2, off);
        a3 += __shfl_down(a3, off);
        c0 += __shfl_down(c0, off);
        c1 += __shfl_down(c1, off);
    }
    if (lane == 0) {
        sred[w][0] = a0; sred[w][1] = a1; sred[w][2] = a2;
        sred[w][3] = a3; sred[w][4] = c0; sred[w][5] = c1;
    }
    __syncthreads();
    if (t == 0) {
        double s[6] = {0, 0, 0, 0, 0, 0};
        for (int i = 0; i < 4; i++)
            for (int j = 0; j < 6; j++) s[j] += sred[i][j];
        double n = s[0] + s[1];
        out[0] = (float)(s[3] / n);            // objectness_loss
        out[1] = (float)(s[2] / n);            // rpn_box_loss
        out[2] = (float)(s[4] / (double)NP);   // classification_loss
        out[3] = (float)(s[5] / (double)NP);   // roi_box_loss
    }
}

extern "C" void kernel_launch(void* const* d_in, const int* in_sizes, int n_in,
                              void* d_out, int out_size, void* d_ws, size_t ws_size,
                              hipStream_t stream) {
    const float4* anchors = (const float4*)d_in[0];
    const float4* gt      = (const float4*)d_in[1];
    const float*  gscore  = (const float*)d_in[2];
    const int*    gconf   = (const int*)d_in[3];
    const float*  objness = (const float*)d_in[4];
    const float4* pdel    = (const float4*)d_in[5];
    const float*  clog    = (const float*)d_in[6];
    const float*  breg    = (const float*)d_in[7];
    const int*    rlab    = (const int*)d_in[8];
    const float4* rtgt    = (const float4*)d_in[9];
    const float*  rsc     = (const float*)d_in[10];

    float* ws = (float*)d_ws;
    float* out = (float*)d_out;

    kA<<<KA_BLOCKS, 256, 0, stream>>>(anchors, gt, gscore, gconf, clog, breg,
                                      rlab, rtgt, rsc, ws);
    kB<<<BBLK, 256, 0, stream>>>(anchors, objness, pdel,
                                 ws + OFF_GTP, (const float4*)(ws + OFF_BEST),
                                 ws + OFF_SUM);
    kC<<<1, 256, 0, stream>>>(ws, out);
}

// Round 6
// 111.377 us; speedup vs baseline: 1.5167x; 1.0037x over previous
//
#include <hip/hip_runtime.h>
#include <hip/hip_bf16.h>
#include <math.h>

#define NA 250000
#define NG 64
#define NP 4096

#define SPAN 512                        // anchors per scan block
#define NB ((NA + SPAN - 1) / SPAN)     // 489 scan blocks
#define NBP 512                         // padded best-table width
#define RBLK (NP / 256)                 // 16 ROI blocks (appended to kA)

// ws float layout
#define OFF_TAB    0                             // [NG][NBP] per-(g,block) max
#define OFF_MAXARG (OFF_TAB + NG * NBP)          // float2 per anchor: (max, arg bits)
#define OFF_FORCE  (OFF_MAXARG + 2 * NB * SPAN)  // byte per anchor
#define FORCE_FLOATS ((NB * SPAN) / 4)
#define OFF_ROI    (OFF_FORCE + FORCE_FLOATS)    // 16 x 2
#define OFF_SUM    (OFF_ROI + RBLK * 2)          // NB x 4

// ---------- shared math helpers ----------

// IoU and areas must be bitwise identical between kA (scan) and kF (force
// re-scan): contraction pinned off; identical inlined op sequences.
static __device__ __forceinline__ float area_of(float4 b) {
#pragma clang fp contract(off)
    return (b.z - b.x) * (b.w - b.y);
}

static __device__ __forceinline__ float iou_one(
    float gx0, float gy0, float gx1, float gy1, float ga,
    float ax0, float ay0, float ax1, float ay1, float aa)
{
#pragma clang fp contract(off)
    float ltx = fmaxf(gx0, ax0);
    float lty = fmaxf(gy0, ay0);
    float rbx = fminf(gx1, ax1);
    float rby = fminf(gy1, ay1);
    float w = fmaxf(rbx - ltx, 0.0f);
    float h = fmaxf(rby - lty, 0.0f);
    float inter = w * h;
    float uni = ga + aa - inter;
    return inter * __builtin_amdgcn_rcpf(uni);   // uni > 0 always
}

static __device__ __forceinline__ float smooth_l1_f(float d) {
    const float BETA = 1.0f / 9.0f;
    float ad = fabsf(d);
    return (ad < BETA) ? (0.5f * d * d / BETA) : (ad - 0.5f * BETA);
}

// ---------- kernel A: unified anchor-major scan (+ROI blocks) ----------
// blocks [0,NB): per-anchor max/argmax -> maxarg; per-(g,block) max -> table;
//               zero own force span.
// blocks [NB,NB+RBLK): ROI losses -> OFF_ROI; zero table pad columns.

__global__ __launch_bounds__(256) void kA(const float4* __restrict__ anchors,
                                          const float4* __restrict__ gt,
                                          const float* __restrict__ logits,
                                          const float* __restrict__ breg,
                                          const int* __restrict__ rlab,
                                          const float4* __restrict__ rtgt,
                                          const float* __restrict__ rsc,
                                          float* __restrict__ ws) {
    int t = threadIdx.x;
    int b = blockIdx.x;

    if (b >= NB) {
        // ---- ROI block ----
        int r = b - NB;
        // zero table pad columns for rows [4r, 4r+4)
        if (t < NBP - NB) {
#pragma unroll
            for (int row = 0; row < 4; row++)
                ws[OFF_TAB + (4 * r + row) * NBP + NB + t] = 0.0f;
        }
        __shared__ float rbuf[4][2];
        int p = r * 256 + t;                 // 16*256 == NP
        float l0 = logits[2 * p], l1 = logits[2 * p + 1];
        float mx = fmaxf(l0, l1);
        float lse = mx + __logf(__expf(l0 - mx) + __expf(l1 - mx));
        float s = rsc[p];
        float clsl = -((1.0f - s) * (l0 - lse) + s * (l1 - lse));

        int lbl = rlab[p];
        int cl = lbl < 0 ? 0 : lbl;
        float4 bb = *(const float4*)(breg + 8 * p + 4 * cl);
        float4 tg = rtgt[p];
        float sl = smooth_l1_f(bb.x - tg.x) + smooth_l1_f(bb.y - tg.y) +
                   smooth_l1_f(bb.z - tg.z) + smooth_l1_f(bb.w - tg.w);
        float boxl = (lbl > 0) ? sl : 0.0f;

        int lane = t & 63, w = t >> 6;
        for (int off = 32; off > 0; off >>= 1) {
            clsl += __shfl_down(clsl, off);
            boxl += __shfl_down(boxl, off);
        }
        if (lane == 0) { rbuf[w][0] = clsl; rbuf[w][1] = boxl; }
        __syncthreads();
        if (t == 0) {
            float s0 = 0.f, s1 = 0.f;
            for (int i = 0; i < 4; i++) { s0 += rbuf[i][0]; s1 += rbuf[i][1]; }
            ws[OFF_ROI + 2 * r] = s0;
            ws[OFF_ROI + 2 * r + 1] = s1;
        }
        return;
    }

    // ---- scan block ----
    // zero own force span (512 bytes = 128 dwords)
    unsigned* fz = (unsigned*)(ws + OFF_FORCE);
    if (t < 128) fz[b * 128 + t] = 0u;

    int a0 = b * SPAN + t;
    int a1 = a0 + 256;
    bool ok0 = a0 < NA, ok1 = a1 < NA;
    float4 av0 = ok0 ? anchors[a0] : make_float4(0.f, 0.f, 0.f, 0.f);
    float4 av1 = ok1 ? anchors[a1] : make_float4(0.f, 0.f, 0.f, 0.f);
    float aa0 = area_of(av0);
    float aa1 = area_of(av1);

    float m[NG];
#pragma unroll
    for (int g = 0; g < NG; g++) m[g] = 0.0f;

    float max0 = -1.0f, max1 = -1.0f;
    int arg0 = 0, arg1 = 0;
#pragma unroll
    for (int g = 0; g < NG; g++) {
        float4 G = gt[g];                    // uniform -> s_load
        float ga = area_of(G);
        float u0 = iou_one(G.x, G.y, G.z, G.w, ga, av0.x, av0.y, av0.z, av0.w, aa0);
        float u1 = iou_one(G.x, G.y, G.z, G.w, ga, av1.x, av1.y, av1.z, av1.w, aa1);
        if (u0 > max0) { max0 = u0; arg0 = g; }   // first-max == jnp.argmax
        if (u1 > max1) { max1 = u1; arg1 = g; }
        m[g] = fmaxf(m[g], fmaxf(u0, u1));        // fake anchors give 0: harmless
    }

    float2* ma = (float2*)(ws + OFF_MAXARG);
    if (ok0) ma[a0] = make_float2(max0, __int_as_float(arg0));
    if (ok1) ma[a1] = make_float2(max1, __int_as_float(arg1));

    // per-(g,block) reduce: 6 shuffles per g, then 4-wave LDS combine
    __shared__ float sred[4][NG];
    int lane = t & 63, w = t >> 6;
#pragma unroll
    for (int g = 0; g < NG; g++) {
        float mm = m[g];
        for (int off = 32; off > 0; off >>= 1)
            mm = fmaxf(mm, __shfl_down(mm, off));
        if (lane == 0) sred[w][g] = mm;
    }
    __syncthreads();
    if (t < NG) {
        float mm = fmaxf(fmaxf(sred[0][t], sred[1][t]),
                         fmaxf(sred[2][t], sred[3][t]));
        ws[OFF_TAB + t * NBP + b] = mm;      // plain store
    }
}

// ---------- kernel F: force detection (64 blocks, one per GT) ----------
// block g: reduce its table row -> best_g; re-scan only the anchor spans
// whose block max equals best_g; set force bytes where iou == best_g.

__global__ __launch_bounds__(256) void kF(const float4* __restrict__ anchors,
                                          const float4* __restrict__ gt,
                                          float* __restrict__ ws) {
    __shared__ float srow[NBP];
    __shared__ float swm[4];
    __shared__ float sbest;
    __shared__ int scnt;
    __shared__ int slist[NBP];
    int t = threadIdx.x;
    int g = blockIdx.x;
    int lane = t & 63, w = t >> 6;

    const float* row = ws + OFF_TAB + g * NBP;
    float v0 = row[t], v1 = row[t + 256];
    srow[t] = v0; srow[t + 256] = v1;
    float mm = fmaxf(v0, v1);
    for (int off = 32; off > 0; off >>= 1)
        mm = fmaxf(mm, __shfl_down(mm, off));
    if (lane == 0) swm[w] = mm;
    if (t == 0) scnt = 0;
    __syncthreads();
    if (t == 0)
        sbest = fmaxf(fmaxf(swm[0], swm[1]), fmaxf(swm[2], swm[3]));
    __syncthreads();
    float best = sbest;

    if (srow[t] == best)       { int i = atomicAdd(&scnt, 1); slist[i] = t; }
    if (srow[t + 256] == best) { int i = atomicAdd(&scnt, 1); slist[i] = t + 256; }
    __syncthreads();

    float4 G = gt[g];                        // uniform -> s_load
    float ga = area_of(G);
    char* fb = (char*)(ws + OFF_FORCE);
    int cnt = scnt;
    for (int i = 0; i < cnt; i++) {
        int s = slist[i];
        int a0 = s * SPAN + t;
        int a1 = a0 + 256;
        if (a0 < NA) {
            float4 av = anchors[a0];
            float u = iou_one(G.x, G.y, G.z, G.w, ga, av.x, av.y, av.z, av.w,
                              area_of(av));
            if (u == best) fb[a0] = 1;       // write-write race benign (same value)
        }
        if (a1 < NA) {
            float4 av = anchors[a1];
            float u = iou_one(G.x, G.y, G.z, G.w, ga, av.x, av.y, av.z, av.w,
                              area_of(av));
            if (u == best) fb[a1] = 1;
        }
    }
}

// ---------- kernel B: per-anchor epilogue + losses (no GT loop) ----------

__global__ __launch_bounds__(256) void kB(const float4* __restrict__ anchors,
                                          const float* __restrict__ objness,
                                          const float4* __restrict__ pdel,
                                          const float4* __restrict__ gt,
                                          const float* __restrict__ gscore,
                                          const int* __restrict__ gconf,
                                          float* __restrict__ ws) {
    __shared__ float rbuf[4][4];
    int t = threadIdx.x;
    int b = blockIdx.x;
    int lane = t & 63, w = t >> 6;
    const float2* ma = (const float2*)(ws + OFF_MAXARG);
    const char* fb = (const char*)(ws + OFF_FORCE);

    float posf = 0.f, negf = 0.f, slpos = 0.f, bces = 0.f;
#pragma unroll
    for (int k = 0; k < 2; k++) {
        int a = b * SPAN + k * 256 + t;
        if (a >= NA) continue;
        float2 mv = ma[a];
        float maxv = mv.x;
        int arg = __float_as_int(mv.y);
        bool force = fb[a] != 0;

        int matched = (maxv < 0.3f) ? -1 : ((maxv < 0.7f) ? -2 : arg);
        if (force) matched = arg;
        int cl = matched < 0 ? 0 : matched;

        float4 Ac = gt[cl];                  // per-lane gather, 1KB L1-hot
        float score = gscore[cl];
        int conf = gconf[cl];
        float label = (matched >= 0) ? 1.0f : 0.0f;
        label = fminf(label, score);
        if (matched == -1) label = 0.0f;
        if (matched == -2) label = -1.0f;
        if (conf == 0 && matched >= 0) label = -1.0f;

        bool pos = (label >= 1.0f);
        bool neg = (label == 0.0f);
        bool sel = pos || neg;

        float4 av = anchors[a];
        float aw = av.z - av.x, ah = av.w - av.y;
        float acx = av.x + 0.5f * aw, acy = av.y + 0.5f * ah;
        float gw = Ac.z - Ac.x, gh = Ac.w - Ac.y;
        float gcx = Ac.x + 0.5f * gw, gcy = Ac.y + 0.5f * gh;
        float t0 = (gcx - acx) / aw;
        float t1 = (gcy - acy) / ah;
        float t2 = __logf(gw / aw);
        float t3 = __logf(gh / ah);

        float4 pd = pdel[a];
        float sl = smooth_l1_f(pd.x - t0) + smooth_l1_f(pd.y - t1) +
                   smooth_l1_f(pd.z - t2) + smooth_l1_f(pd.w - t3);

        float x = objness[a];
        float y = sel ? fminf(fmaxf(label, 0.0f), 1.0f) : 0.0f;
        float bce = fmaxf(x, 0.0f) - x * y + __logf(1.0f + __expf(-fabsf(x)));

        if (pos) { posf += 1.0f; slpos += sl; }
        if (neg) negf += 1.0f;
        if (sel) bces += bce;
    }

    for (int off = 32; off > 0; off >>= 1) {
        posf  += __shfl_down(posf, off);
        negf  += __shfl_down(negf, off);
        slpos += __shfl_down(slpos, off);
        bces  += __shfl_down(bces, off);
    }
    if (lane == 0) { rbuf[w][0] = posf; rbuf[w][1] = negf; rbuf[w][2] = slpos; rbuf[w][3] = bces; }
    __syncthreads();
    if (t == 0) {
        float s0 = 0.f, s1 = 0.f, s2 = 0.f, s3 = 0.f;
        for (int i = 0; i < 4; i++) { s0 += rbuf[i][0]; s1 += rbuf[i][1]; s2 += rbuf[i][2]; s3 += rbuf[i][3]; }
        float* r = ws + OFF_SUM + 4 * b;
        r[0] = s0; r[1] = s1; r[2] = s2; r[3] = s3;   // plain stores
    }
}

// ---------- kernel C: final reduce (1 block, doubles) ----------

__global__ __launch_bounds__(256) void kC(const float* __restrict__ ws,
                                          float* __restrict__ out) {
    __shared__ double sred[4][6];
    int t = threadIdx.x;
    int lane = t & 63, w = t >> 6;
    double a0 = 0, a1 = 0, a2 = 0, a3 = 0, c0 = 0, c1 = 0;
    for (int r = t; r < NB; r += 256) {
        const float4 v = *(const float4*)(ws + OFF_SUM + 4 * r);
        a0 += v.x; a1 += v.y; a2 += v.z; a3 += v.w;
    }
    if (t < RBLK) {
        c0 = ws[OFF_ROI + 2 * t];
        c1 = ws[OFF_ROI + 2 * t + 1];
    }
    for (int off = 32; off > 0; off >>= 1) {
        a0 += __shfl_down(a0, off);
        a1 += __shfl_down(a1, off);
        a2 += __shfl_down(a2, off);
        a3 += __shfl_down(a3, off);
        c0 += __shfl_down(c0, off);
        c1 += __shfl_down(c1, off);
    }
    if (lane == 0) {
        sred[w][0] = a0; sred[w][1] = a1; sred[w][2] = a2;
        sred[w][3] = a3; sred[w][4] = c0; sred[w][5] = c1;
    }
    __syncthreads();
    if (t == 0) {
        double s[6] = {0, 0, 0, 0, 0, 0};
        for (int i = 0; i < 4; i++)
            for (int j = 0; j < 6; j++) s[j] += sred[i][j];
        double n = s[0] + s[1];
        out[0] = (float)(s[3] / n);            // objectness_loss
        out[1] = (float)(s[2] / n);            // rpn_box_loss
        out[2] = (float)(s[4] / (double)NP);   // classification_loss
        out[3] = (float)(s[5] / (double)NP);   // roi_box_loss
    }
}

extern "C" void kernel_launch(void* const* d_in, const int* in_sizes, int n_in,
                              void* d_out, int out_size, void* d_ws, size_t ws_size,
                              hipStream_t stream) {
    const float4* anchors = (const float4*)d_in[0];
    const float4* gt      = (const float4*)d_in[1];
    const float*  gscore  = (const float*)d_in[2];
    const int*    gconf   = (const int*)d_in[3];
    const float*  objness = (const float*)d_in[4];
    const float4* pdel    = (const float4*)d_in[5];
    const float*  clog    = (const float*)d_in[6];
    const float*  breg    = (const float*)d_in[7];
    const int*    rlab    = (const int*)d_in[8];
    const float4* rtgt    = (const float4*)d_in[9];
    const float*  rsc     = (const float*)d_in[10];

    float* ws = (float*)d_ws;
    float* out = (float*)d_out;

    kA<<<NB + RBLK, 256, 0, stream>>>(anchors, gt, clog, breg, rlab, rtgt, rsc, ws);
    kF<<<NG, 256, 0, stream>>>(anchors, gt, ws);
    kB<<<NB, 256, 0, stream>>>(anchors, objness, pdel, gt, gscore, gconf, ws);
    kC<<<1, 256, 0, stream>>>(ws, out);
}